// Round 4
// baseline (5463.475 us; speedup 1.0000x reference)
//
#include <hip/hip_runtime.h>

// Problem constants
#define TT 20
#define NNODE 512
#define G2C 16
#define RCH 128
#define ECH 64
#define ICH 2
#define OCH 5
#define KSOC 8192          // N*G2
#define KSPLIT 16
#define KCH 512            // KSOC/KSPLIT
#define SGS 516            // LDS f32 row stride in social phase (conflict-free)
#define NBLK 512

// workspace layout (double offsets)
#define OFF_H    0u         // h   [512*128]
#define OFF_C    65536u     // c   [512*128]
#define OFF_HT   131072u    // Ht  [8192][64]
#define OFF_PART 655360u    // part[16][512][64]
#define OFF_WCAT 1179648u   // Wcat[512 gc][256 kk] (kk<128: W_ih, kk>=128: W_hh)
#define OFF_WTT  1310720u   // WtT [2048 q2][64 e]  q2 = g*128+r
#define OFF_BS   1441792u   // bs  [512 gc]
#define OFF_BAR  1442304u   // barrier: 2 unsigned
// total ~11.54 MB

__device__ __forceinline__ double sigd(double x){ return 1.0/(1.0+exp(-x)); }

__global__ void k_init(const float* __restrict__ h0, const float* __restrict__ c0,
                       const float* __restrict__ W_ih, const float* __restrict__ b_ih,
                       const float* __restrict__ W_hh, const float* __restrict__ b_hh,
                       const float* __restrict__ W_tensor, double* __restrict__ ws) {
  int tid = blockIdx.x*blockDim.x + threadIdx.x;
  int nthr = gridDim.x*blockDim.x;
  double* h = ws + OFF_H; double* c = ws + OFF_C;
  double* Wcat = ws + OFF_WCAT; double* WtT = ws + OFF_WTT;
  double* bs = ws + OFF_BS;
  if (tid == 0) { unsigned* bar = (unsigned*)(ws + OFF_BAR); bar[0] = 0u; bar[1] = 0u; }
  for (int i = tid; i < NNODE*RCH; i += nthr) { h[i] = (double)h0[i]; c[i] = (double)c0[i]; }
  for (int i = tid; i < 512*256; i += nthr) {
    int kk = i & 255; int gc = i >> 8;
    Wcat[i] = (kk < 128) ? (double)W_ih[gc*128 + kk] : (double)W_hh[gc*128 + (kk-128)];
  }
  for (int i = tid; i < 2048*64; i += nthr) {
    int e = i & 63; int q2 = i >> 6;
    WtT[i] = (double)W_tensor[e*2048 + q2];
  }
  for (int i = tid; i < 512; i += nthr) bs[i] = (double)b_ih[i] + (double)b_hh[i];
}

// device-scope grid barrier (all NBLK blocks co-resident by construction)
__device__ __forceinline__ void grid_sync(unsigned* bar, unsigned gen) {
  __syncthreads();
  if (threadIdx.x == 0) {
    unsigned prev = __hip_atomic_fetch_add(&bar[0], 1u, __ATOMIC_ACQ_REL,
                                           __HIP_MEMORY_SCOPE_AGENT);
    if (prev == NBLK-1u) {
      __hip_atomic_store(&bar[0], 0u, __ATOMIC_RELAXED, __HIP_MEMORY_SCOPE_AGENT);
      __hip_atomic_store(&bar[1], gen+1u, __ATOMIC_RELEASE, __HIP_MEMORY_SCOPE_AGENT);
    } else {
      while (__hip_atomic_load(&bar[1], __ATOMIC_ACQUIRE,
                               __HIP_MEMORY_SCOPE_AGENT) != gen+1u)
        __builtin_amdgcn_s_sleep(2);
    }
  }
  __syncthreads();
}

__global__ __launch_bounds__(256, 2) void k_steps(
    const float* __restrict__ nodes, const float* __restrict__ grids,
    const float* __restrict__ W_in, const float* __restrict__ b_in,
    const float* __restrict__ b_tensor,
    const float* __restrict__ W_out, const float* __restrict__ b_out,
    double* __restrict__ ws, float* __restrict__ outp,
    float* __restrict__ hf, float* __restrict__ cf) {
  __shared__ __align__(16) double smem[4672];
  double* __restrict__ h = ws + OFF_H;
  double* __restrict__ c = ws + OFF_C;
  double* __restrict__ Ht = ws + OFF_HT;
  double* __restrict__ part = ws + OFF_PART;
  const double* __restrict__ Wcat = ws + OFF_WCAT;
  const double* __restrict__ WtT = ws + OFF_WTT;
  const double* __restrict__ bs = ws + OFF_BS;
  unsigned* bar = (unsigned*)(ws + OFF_BAR);
  const int tid = threadIdx.x;
  const int bid = blockIdx.x;
  unsigned gen = 0;

  // ---- phase HT(t=0): Ht from h(0); no out ----
  {
    double (*h2b)[130] = (double(*)[130])smem;
    const int mc = bid >> 4, g = bid & 15;
    const int m0 = mc << 4;
    const int r = tid & 127;
    #pragma unroll
    for (int pass = 0; pass < 8; ++pass) {
      const int n = (tid >> 7) + (pass << 1);
      h2b[n][r] = h[(size_t)(m0+n)*RCH + r];
    }
    __syncthreads();
    const int e = tid & 63, mh = tid >> 6;
    const double* wt = WtT + (size_t)(g*128)*ECH + e;
    double acc[4] = {};
    #pragma unroll 4
    for (int rr = 0; rr < 128; ++rr) {
      double w0 = wt[(size_t)rr*ECH];
      #pragma unroll
      for (int mi = 0; mi < 4; ++mi) acc[mi] += h2b[(mh<<2)+mi][rr]*w0;
    }
    #pragma unroll
    for (int mi = 0; mi < 4; ++mi)
      Ht[((size_t)(m0+(mh<<2)+mi)*G2C + g)*ECH + e] = acc[mi];
  }
  grid_sync(bar, gen); ++gen;

  for (int t = 0; t < TT; ++t) {
    // ---- phase SOCIAL: part[kc][n][e] ----
    {
      float* sgf = (float*)smem;
      const int kc = bid & (KSPLIT-1);
      const int n0 = (bid >> 4) << 4;
      const int kb = kc * KCH;
      const float* gbase = grids + (size_t)t*NNODE*KSOC;
      for (int i = tid; i < 16*128; i += 256) {
        int row = i >> 7; int c4 = i & 127;
        float4 v = *(const float4*)(gbase + (size_t)(n0+row)*KSOC + kb + (c4<<2));
        *(float4*)(&sgf[row*SGS + (c4<<2)]) = v;
      }
      __syncthreads();
      const int lane = tid & 63;
      const int wv = tid >> 6;
      const int e0 = (lane & 15) << 2;
      const int nq = lane >> 4;
      double acc[4][4] = {};
      const int kl0 = wv << 7;
      const double* htp = Ht + (size_t)(kb + kl0)*ECH + e0;
      #pragma unroll 2
      for (int kk = 0; kk < 128; kk += 2) {
        double2 b0a = *(const double2*)(htp + (size_t)kk*ECH);
        double2 b0b = *(const double2*)(htp + (size_t)kk*ECH + 2);
        double2 b1a = *(const double2*)(htp + (size_t)(kk+1)*ECH);
        double2 b1b = *(const double2*)(htp + (size_t)(kk+1)*ECH + 2);
        const int kl = kl0 + kk;
        #pragma unroll
        for (int jn = 0; jn < 4; ++jn) {
          float2 av2 = *(const float2*)(&sgf[((jn<<2)+nq)*SGS + kl]);
          double a0 = (double)av2.x, a1 = (double)av2.y;
          acc[jn][0] += a0*b0a.x + a1*b1a.x;
          acc[jn][1] += a0*b0a.y + a1*b1a.y;
          acc[jn][2] += a0*b0b.x + a1*b1b.x;
          acc[jn][3] += a0*b0b.y + a1*b1b.y;
        }
      }
      __syncthreads();
      if (wv > 0) {
        double* rp = smem + ((size_t)(wv-1)*64 + lane)*16;
        #pragma unroll
        for (int jn = 0; jn < 4; ++jn)
          #pragma unroll
          for (int je = 0; je < 4; ++je) rp[(jn<<2)+je] = acc[jn][je];
      }
      __syncthreads();
      if (wv == 0) {
        #pragma unroll
        for (int w = 0; w < 3; ++w) {
          const double* rp = smem + ((size_t)w*64 + lane)*16;
          #pragma unroll
          for (int jn = 0; jn < 4; ++jn)
            #pragma unroll
            for (int je = 0; je < 4; ++je) acc[jn][je] += rp[(jn<<2)+je];
        }
        #pragma unroll
        for (int jn = 0; jn < 4; ++jn) {
          double* pp = part + ((size_t)kc*NNODE + n0 + (jn<<2) + nq)*ECH + e0;
          pp[0]=acc[jn][0]; pp[1]=acc[jn][1]; pp[2]=acc[jn][2]; pp[3]=acc[jn][3];
        }
      }
    }
    grid_sync(bar, gen); ++gen;

    // ---- phase CELL: gates + pointwise ----
    {
      double (*xh)[258] = (double(*)[258])smem;          // 16*258 = 4128
      double (*gbuf)[17] = (double(*)[17])(smem + 4128); // 32*17  = 544
      const int nc = bid >> 4;
      const int rc = bid & 15;
      const int m0 = nc << 4;
      {
        const int e = tid & 63;
        #pragma unroll
        for (int pass = 0; pass < 4; ++pass) {
          const int n = (tid >> 6) + (pass << 2);
          const int m = m0 + n;
          double te = (double)b_tensor[e];
          for (int kc = 0; kc < KSPLIT; ++kc)
            te += part[((size_t)kc*NNODE + m)*ECH + e];
          double n0v = (double)nodes[((size_t)t*NNODE + m)*ICH + 0];
          double n1v = (double)nodes[((size_t)t*NNODE + m)*ICH + 1];
          double ie = n0v*(double)W_in[e*2] + n1v*(double)W_in[e*2+1] + (double)b_in[e];
          xh[n][e] = fmax(ie, 0.0);
          xh[n][64+e] = fmax(te, 0.0);
        }
        const int r = tid & 127;
        #pragma unroll
        for (int pass = 0; pass < 8; ++pass) {
          const int n = (tid >> 7) + (pass << 1);
          xh[n][128+r] = h[(size_t)(m0+n)*RCH + r];
        }
      }
      __syncthreads();
      {
        const int n = tid & 15, tg = tid >> 4;
        const int q0 = tg >> 3, jr = tg & 7;
        const int gc0 = q0*128 + rc*8 + jr;
        const int gc1 = (q0+2)*128 + rc*8 + jr;
        const double* w0 = Wcat + (size_t)gc0*256;
        const double* w1 = Wcat + (size_t)gc1*256;
        double a0 = 0.0, a1 = 0.0;
        #pragma unroll 8
        for (int kk = 0; kk < 256; kk += 2) {
          double2 xv = *(const double2*)(&xh[n][kk]);
          double2 wa = *(const double2*)(w0 + kk);
          double2 wb = *(const double2*)(w1 + kk);
          a0 += xv.x*wa.x + xv.y*wa.y;
          a1 += xv.x*wb.x + xv.y*wb.y;
        }
        gbuf[tg][n]    = a0 + bs[gc0];
        gbuf[tg+16][n] = a1 + bs[gc1];
      }
      __syncthreads();
      if (tid < 128) {
        const int n = tid >> 3, jr = tid & 7;
        const int m = m0 + n, r = rc*8 + jr;
        double ig = sigd(gbuf[jr][n]);
        double fg = sigd(gbuf[8+jr][n]);
        double gg = tanh(gbuf[16+jr][n]);
        double og = sigd(gbuf[24+jr][n]);
        double cold = c[(size_t)m*RCH + r];
        double c2 = fg*cold + ig*gg;
        double h2v = og*tanh(c2);
        c[(size_t)m*RCH + r] = c2;
        h[(size_t)m*RCH + r] = h2v;
        if (t == TT-1) {
          hf[(size_t)m*RCH + r] = (float)h2v;
          cf[(size_t)m*RCH + r] = (float)c2;
        }
      }
    }
    grid_sync(bar, gen); ++gen;

    // ---- phase HT+OUT: Ht(t+1) (skip at last t) + out[t] ----
    {
      double (*h2b)[130] = (double(*)[130])smem;
      const int mc = bid >> 4, g = bid & 15;
      const int m0 = mc << 4;
      const int r = tid & 127;
      #pragma unroll
      for (int pass = 0; pass < 8; ++pass) {
        const int n = (tid >> 7) + (pass << 1);
        h2b[n][r] = h[(size_t)(m0+n)*RCH + r];
      }
      __syncthreads();
      if (t < TT-1) {
        const int e = tid & 63, mh = tid >> 6;
        const double* wt = WtT + (size_t)(g*128)*ECH + e;
        double acc[4] = {};
        #pragma unroll 4
        for (int rr = 0; rr < 128; ++rr) {
          double w0 = wt[(size_t)rr*ECH];
          #pragma unroll
          for (int mi = 0; mi < 4; ++mi) acc[mi] += h2b[(mh<<2)+mi][rr]*w0;
        }
        #pragma unroll
        for (int mi = 0; mi < 4; ++mi)
          Ht[((size_t)(m0+(mh<<2)+mi)*G2C + g)*ECH + e] = acc[mi];
      }
      if (g == 0 && tid < 80) {
        const int mi = tid / OCH, oo = tid % OCH;
        double v = (double)b_out[oo];
        #pragma unroll 8
        for (int r2 = 0; r2 < 128; ++r2)
          v += h2b[mi][r2]*(double)W_out[oo*RCH + r2];
        outp[((size_t)t*NNODE + m0 + mi)*OCH + oo] = (float)v;
      }
    }
    if (t < TT-1) { grid_sync(bar, gen); ++gen; }
  }
}

extern "C" void kernel_launch(void* const* d_in, const int* in_sizes, int n_in,
                              void* d_out, int out_size, void* d_ws, size_t ws_size,
                              hipStream_t stream) {
  const float* nodes    = (const float*)d_in[0];
  const float* grids    = (const float*)d_in[1];
  const float* h0       = (const float*)d_in[2];
  const float* c0       = (const float*)d_in[3];
  const float* W_in     = (const float*)d_in[4];
  const float* b_in     = (const float*)d_in[5];
  const float* W_tensor = (const float*)d_in[6];
  const float* b_tensor = (const float*)d_in[7];
  const float* W_ih     = (const float*)d_in[8];
  const float* b_ih     = (const float*)d_in[9];
  const float* W_hh     = (const float*)d_in[10];
  const float* b_hh     = (const float*)d_in[11];
  const float* W_out    = (const float*)d_in[12];
  const float* b_out    = (const float*)d_in[13];
  double* ws = (double*)d_ws;
  float* outp = (float*)d_out;                 // [20][512][5]
  float* hf = outp + (size_t)TT*NNODE*OCH;     // [512][128]
  float* cf = hf + (size_t)NNODE*RCH;          // [512][128]

  k_init<<<256, 256, 0, stream>>>(h0, c0, W_ih, b_ih, W_hh, b_hh, W_tensor, ws);
  k_steps<<<NBLK, 256, 0, stream>>>(nodes, grids, W_in, b_in, b_tensor,
                                    W_out, b_out, ws, outp, hf, cf);
}

// Round 5
// 3226.866 us; speedup vs baseline: 1.6931x; 1.6931x over previous
//
#include <hip/hip_runtime.h>

// Problem constants
#define TT 20
#define NNODE 512
#define G2C 16
#define RCH 128
#define ECH 64
#define ICH 2
#define OCH 5
#define KSOC 8192          // N*G2
#define KSPLIT 16
#define KCH 512            // KSOC/KSPLIT
#define SGS 516            // LDS f32 row stride in social phase (conflict-free)
#define NBLK 512
#define NLEAF 8

// workspace layout (double offsets)
#define OFF_H    0u         // h   [512*128]
#define OFF_C    65536u     // c   [512*128]
#define OFF_HT   131072u    // Ht  [8192][64]
#define OFF_PART 655360u    // part[16][512][64]
#define OFF_WCAT 1179648u   // Wcat[512 gc][256 kk] (kk<128: W_ih, kk>=128: W_hh)
#define OFF_WTT  1310720u   // WtT [2048 q2][64 e]  q2 = g*128+r
#define OFF_BS   1441792u   // bs  [512 gc]
#define OFF_BAR  1442304u   // barrier: leaves[8*16] + root@128 + gate@144 (unsigned)
// total ~11.54 MB

__device__ __forceinline__ double sigd(double x){ return 1.0/(1.0+exp(-x)); }

__global__ void k_init(const float* __restrict__ h0, const float* __restrict__ c0,
                       const float* __restrict__ W_ih, const float* __restrict__ b_ih,
                       const float* __restrict__ W_hh, const float* __restrict__ b_hh,
                       const float* __restrict__ W_tensor, double* __restrict__ ws) {
  int tid = blockIdx.x*blockDim.x + threadIdx.x;
  int nthr = gridDim.x*blockDim.x;
  double* h = ws + OFF_H; double* c = ws + OFF_C;
  double* Wcat = ws + OFF_WCAT; double* WtT = ws + OFF_WTT;
  double* bs = ws + OFF_BS;
  if (tid < 160) ((unsigned*)(ws + OFF_BAR))[tid] = 0u;
  for (int i = tid; i < NNODE*RCH; i += nthr) { h[i] = (double)h0[i]; c[i] = (double)c0[i]; }
  for (int i = tid; i < 512*256; i += nthr) {
    int kk = i & 255; int gc = i >> 8;
    Wcat[i] = (kk < 128) ? (double)W_ih[gc*128 + kk] : (double)W_hh[gc*128 + (kk-128)];
  }
  for (int i = tid; i < 2048*64; i += nthr) {
    int e = i & 63; int q2 = i >> 6;
    WtT[i] = (double)W_tensor[e*2048 + q2];
  }
  for (int i = tid; i < 512; i += nthr) bs[i] = (double)b_ih[i] + (double)b_hh[i];
}

// Device-scope grid barrier. All coherence ops happen ONCE per block per barrier:
// release fence (wbl2) before arrival, acquire fence (inv) after gate opens.
// Polls are RELAXED (no cache maintenance). Hierarchical counters cut contention.
__device__ __forceinline__ void grid_sync(unsigned* bar, unsigned gen, int bid) {
  __syncthreads();
  if (threadIdx.x == 0) {
    __builtin_amdgcn_fence(__ATOMIC_RELEASE, "agent");
    unsigned* leaf = bar + ((bid & (NLEAF-1)) << 4);
    unsigned prev = __hip_atomic_fetch_add(leaf, 1u, __ATOMIC_RELAXED,
                                           __HIP_MEMORY_SCOPE_AGENT);
    if (prev == (NBLK/NLEAF)-1u) {
      unsigned pr = __hip_atomic_fetch_add(bar+128, 1u, __ATOMIC_RELAXED,
                                           __HIP_MEMORY_SCOPE_AGENT);
      if (pr == NLEAF-1u) {
        #pragma unroll
        for (int i = 0; i < NLEAF; ++i)
          __hip_atomic_store(bar + (i<<4), 0u, __ATOMIC_RELAXED, __HIP_MEMORY_SCOPE_AGENT);
        __hip_atomic_store(bar+128, 0u, __ATOMIC_RELAXED, __HIP_MEMORY_SCOPE_AGENT);
        // release orders the resets before the gate-open
        __hip_atomic_store(bar+144, gen+1u, __ATOMIC_RELEASE, __HIP_MEMORY_SCOPE_AGENT);
      }
    }
    while (__hip_atomic_load(bar+144, __ATOMIC_RELAXED,
                             __HIP_MEMORY_SCOPE_AGENT) != gen+1u)
      __builtin_amdgcn_s_sleep(4);
    __builtin_amdgcn_fence(__ATOMIC_ACQUIRE, "agent");
  }
  __syncthreads();
}

__global__ __launch_bounds__(256, 2) void k_steps(
    const float* __restrict__ nodes, const float* __restrict__ grids,
    const float* __restrict__ W_in, const float* __restrict__ b_in,
    const float* __restrict__ b_tensor,
    const float* __restrict__ W_out, const float* __restrict__ b_out,
    double* __restrict__ ws, float* __restrict__ outp,
    float* __restrict__ hf, float* __restrict__ cf) {
  __shared__ __align__(16) double smem[4672];
  double* __restrict__ h = ws + OFF_H;
  double* __restrict__ c = ws + OFF_C;
  double* __restrict__ Ht = ws + OFF_HT;
  double* __restrict__ part = ws + OFF_PART;
  const double* __restrict__ Wcat = ws + OFF_WCAT;
  const double* __restrict__ WtT = ws + OFF_WTT;
  const double* __restrict__ bs = ws + OFF_BS;
  unsigned* bar = (unsigned*)(ws + OFF_BAR);
  const int tid = threadIdx.x;
  const int bid = blockIdx.x;
  unsigned gen = 0;

  // ---- phase HT(t=0): Ht from h(0); no out ----
  {
    double (*h2b)[130] = (double(*)[130])smem;
    const int mc = bid >> 4, g = bid & 15;
    const int m0 = mc << 4;
    const int r = tid & 127;
    #pragma unroll
    for (int pass = 0; pass < 8; ++pass) {
      const int n = (tid >> 7) + (pass << 1);
      h2b[n][r] = h[(size_t)(m0+n)*RCH + r];
    }
    __syncthreads();
    const int e = tid & 63, mh = tid >> 6;
    const double* wt = WtT + (size_t)(g*128)*ECH + e;
    double acc[4] = {};
    #pragma unroll 4
    for (int rr = 0; rr < 128; ++rr) {
      double w0 = wt[(size_t)rr*ECH];
      #pragma unroll
      for (int mi = 0; mi < 4; ++mi) acc[mi] += h2b[(mh<<2)+mi][rr]*w0;
    }
    #pragma unroll
    for (int mi = 0; mi < 4; ++mi)
      Ht[((size_t)(m0+(mh<<2)+mi)*G2C + g)*ECH + e] = acc[mi];
  }
  grid_sync(bar, gen, bid); ++gen;

  for (int t = 0; t < TT; ++t) {
    // ---- phase SOCIAL: part[kc][n][e] ----
    {
      float* sgf = (float*)smem;
      const int kc = bid & (KSPLIT-1);
      const int n0 = (bid >> 4) << 4;
      const int kb = kc * KCH;
      const float* gbase = grids + (size_t)t*NNODE*KSOC;
      for (int i = tid; i < 16*128; i += 256) {
        int row = i >> 7; int c4 = i & 127;
        float4 v = *(const float4*)(gbase + (size_t)(n0+row)*KSOC + kb + (c4<<2));
        *(float4*)(&sgf[row*SGS + (c4<<2)]) = v;
      }
      __syncthreads();
      const int lane = tid & 63;
      const int wv = tid >> 6;
      const int e0 = (lane & 15) << 2;
      const int nq = lane >> 4;
      double acc[4][4] = {};
      const int kl0 = wv << 7;
      const double* htp = Ht + (size_t)(kb + kl0)*ECH + e0;
      #pragma unroll 2
      for (int kk = 0; kk < 128; kk += 2) {
        double2 b0a = *(const double2*)(htp + (size_t)kk*ECH);
        double2 b0b = *(const double2*)(htp + (size_t)kk*ECH + 2);
        double2 b1a = *(const double2*)(htp + (size_t)(kk+1)*ECH);
        double2 b1b = *(const double2*)(htp + (size_t)(kk+1)*ECH + 2);
        const int kl = kl0 + kk;
        #pragma unroll
        for (int jn = 0; jn < 4; ++jn) {
          float2 av2 = *(const float2*)(&sgf[((jn<<2)+nq)*SGS + kl]);
          double a0 = (double)av2.x, a1 = (double)av2.y;
          acc[jn][0] += a0*b0a.x + a1*b1a.x;
          acc[jn][1] += a0*b0a.y + a1*b1a.y;
          acc[jn][2] += a0*b0b.x + a1*b1b.x;
          acc[jn][3] += a0*b0b.y + a1*b1b.y;
        }
      }
      __syncthreads();
      if (wv > 0) {
        double* rp = smem + ((size_t)(wv-1)*64 + lane)*16;
        #pragma unroll
        for (int jn = 0; jn < 4; ++jn)
          #pragma unroll
          for (int je = 0; je < 4; ++je) rp[(jn<<2)+je] = acc[jn][je];
      }
      __syncthreads();
      if (wv == 0) {
        #pragma unroll
        for (int w = 0; w < 3; ++w) {
          const double* rp = smem + ((size_t)w*64 + lane)*16;
          #pragma unroll
          for (int jn = 0; jn < 4; ++jn)
            #pragma unroll
            for (int je = 0; je < 4; ++je) acc[jn][je] += rp[(jn<<2)+je];
        }
        #pragma unroll
        for (int jn = 0; jn < 4; ++jn) {
          double* pp = part + ((size_t)kc*NNODE + n0 + (jn<<2) + nq)*ECH + e0;
          pp[0]=acc[jn][0]; pp[1]=acc[jn][1]; pp[2]=acc[jn][2]; pp[3]=acc[jn][3];
        }
      }
    }
    grid_sync(bar, gen, bid); ++gen;

    // ---- phase CELL: gates + pointwise ----
    {
      double (*xh)[258] = (double(*)[258])smem;          // 16*258 = 4128
      double (*gbuf)[17] = (double(*)[17])(smem + 4128); // 32*17  = 544
      const int nc = bid >> 4;
      const int rc = bid & 15;
      const int m0 = nc << 4;
      {
        const int e = tid & 63;
        #pragma unroll
        for (int pass = 0; pass < 4; ++pass) {
          const int n = (tid >> 6) + (pass << 2);
          const int m = m0 + n;
          double te = (double)b_tensor[e];
          for (int kc = 0; kc < KSPLIT; ++kc)
            te += part[((size_t)kc*NNODE + m)*ECH + e];
          double n0v = (double)nodes[((size_t)t*NNODE + m)*ICH + 0];
          double n1v = (double)nodes[((size_t)t*NNODE + m)*ICH + 1];
          double ie = n0v*(double)W_in[e*2] + n1v*(double)W_in[e*2+1] + (double)b_in[e];
          xh[n][e] = fmax(ie, 0.0);
          xh[n][64+e] = fmax(te, 0.0);
        }
        const int r = tid & 127;
        #pragma unroll
        for (int pass = 0; pass < 8; ++pass) {
          const int n = (tid >> 7) + (pass << 1);
          xh[n][128+r] = h[(size_t)(m0+n)*RCH + r];
        }
      }
      __syncthreads();
      {
        const int n = tid & 15, tg = tid >> 4;
        const int q0 = tg >> 3, jr = tg & 7;
        const int gc0 = q0*128 + rc*8 + jr;
        const int gc1 = (q0+2)*128 + rc*8 + jr;
        const double* w0 = Wcat + (size_t)gc0*256;
        const double* w1 = Wcat + (size_t)gc1*256;
        double a0 = 0.0, a1 = 0.0;
        #pragma unroll 8
        for (int kk = 0; kk < 256; kk += 2) {
          double2 xv = *(const double2*)(&xh[n][kk]);
          double2 wa = *(const double2*)(w0 + kk);
          double2 wb = *(const double2*)(w1 + kk);
          a0 += xv.x*wa.x + xv.y*wa.y;
          a1 += xv.x*wb.x + xv.y*wb.y;
        }
        gbuf[tg][n]    = a0 + bs[gc0];
        gbuf[tg+16][n] = a1 + bs[gc1];
      }
      __syncthreads();
      if (tid < 128) {
        const int n = tid >> 3, jr = tid & 7;
        const int m = m0 + n, r = rc*8 + jr;
        double ig = sigd(gbuf[jr][n]);
        double fg = sigd(gbuf[8+jr][n]);
        double gg = tanh(gbuf[16+jr][n]);
        double og = sigd(gbuf[24+jr][n]);
        double cold = c[(size_t)m*RCH + r];
        double c2 = fg*cold + ig*gg;
        double h2v = og*tanh(c2);
        c[(size_t)m*RCH + r] = c2;
        h[(size_t)m*RCH + r] = h2v;
        if (t == TT-1) {
          hf[(size_t)m*RCH + r] = (float)h2v;
          cf[(size_t)m*RCH + r] = (float)c2;
        }
      }
    }
    grid_sync(bar, gen, bid); ++gen;

    // ---- phase HT+OUT: Ht(t+1) (skip at last t) + out[t] ----
    {
      double (*h2b)[130] = (double(*)[130])smem;
      const int mc = bid >> 4, g = bid & 15;
      const int m0 = mc << 4;
      const int r = tid & 127;
      #pragma unroll
      for (int pass = 0; pass < 8; ++pass) {
        const int n = (tid >> 7) + (pass << 1);
        h2b[n][r] = h[(size_t)(m0+n)*RCH + r];
      }
      __syncthreads();
      if (t < TT-1) {
        const int e = tid & 63, mh = tid >> 6;
        const double* wt = WtT + (size_t)(g*128)*ECH + e;
        double acc[4] = {};
        #pragma unroll 4
        for (int rr = 0; rr < 128; ++rr) {
          double w0 = wt[(size_t)rr*ECH];
          #pragma unroll
          for (int mi = 0; mi < 4; ++mi) acc[mi] += h2b[(mh<<2)+mi][rr]*w0;
        }
        #pragma unroll
        for (int mi = 0; mi < 4; ++mi)
          Ht[((size_t)(m0+(mh<<2)+mi)*G2C + g)*ECH + e] = acc[mi];
      }
      if (g == 0 && tid < 80) {
        const int mi = tid / OCH, oo = tid % OCH;
        double v = (double)b_out[oo];
        #pragma unroll 8
        for (int r2 = 0; r2 < 128; ++r2)
          v += h2b[mi][r2]*(double)W_out[oo*RCH + r2];
        outp[((size_t)t*NNODE + m0 + mi)*OCH + oo] = (float)v;
      }
    }
    if (t < TT-1) { grid_sync(bar, gen, bid); ++gen; }
  }
}

extern "C" void kernel_launch(void* const* d_in, const int* in_sizes, int n_in,
                              void* d_out, int out_size, void* d_ws, size_t ws_size,
                              hipStream_t stream) {
  const float* nodes    = (const float*)d_in[0];
  const float* grids    = (const float*)d_in[1];
  const float* h0       = (const float*)d_in[2];
  const float* c0       = (const float*)d_in[3];
  const float* W_in     = (const float*)d_in[4];
  const float* b_in     = (const float*)d_in[5];
  const float* W_tensor = (const float*)d_in[6];
  const float* b_tensor = (const float*)d_in[7];
  const float* W_ih     = (const float*)d_in[8];
  const float* b_ih     = (const float*)d_in[9];
  const float* W_hh     = (const float*)d_in[10];
  const float* b_hh     = (const float*)d_in[11];
  const float* W_out    = (const float*)d_in[12];
  const float* b_out    = (const float*)d_in[13];
  double* ws = (double*)d_ws;
  float* outp = (float*)d_out;                 // [20][512][5]
  float* hf = outp + (size_t)TT*NNODE*OCH;     // [512][128]
  float* cf = hf + (size_t)NNODE*RCH;          // [512][128]

  k_init<<<256, 256, 0, stream>>>(h0, c0, W_ih, b_ih, W_hh, b_hh, W_tensor, ws);
  k_steps<<<NBLK, 256, 0, stream>>>(nodes, grids, W_in, b_in, b_tensor,
                                    W_out, b_out, ws, outp, hf, cf);
}

// Round 6
// 3164.887 us; speedup vs baseline: 1.7263x; 1.0196x over previous
//
#include <hip/hip_runtime.h>

// Problem constants
#define TT 20
#define NNODE 512
#define G2C 16
#define RCH 128
#define ECH 64
#define ICH 2
#define OCH 5
#define KSOC 8192          // N*G2
#define KSPLIT 16
#define KCH 512            // KSOC/KSPLIT
#define SGS 516            // LDS f32 row stride in social phase (conflict-free)
#define NBLK 512
#define NLEAF 8

// workspace layout (double offsets)
#define OFF_H    0u         // h   [512*128]
#define OFF_C    65536u     // c   [512*128]
#define OFF_HT   131072u    // Ht  [8192][64]
#define OFF_PART 655360u    // part[16][512][64]
#define OFF_WCAT 1179648u   // Wcat[512 gc][256 kk] (kk<128: W_ih, kk>=128: W_hh)
#define OFF_WTT  1310720u   // WtT [2048 q2][64 e]  q2 = g*128+r
#define OFF_BS   1441792u   // bs  [512 gc]
#define OFF_BAR  1442304u   // barrier words: leaf[i]@i*16 (i<8), root@128, gate[i]@160+i*16
// total ~11.54 MB

__device__ __forceinline__ double sigd(double x){ return 1.0/(1.0+exp(-x)); }

__global__ void k_init(const float* __restrict__ h0, const float* __restrict__ c0,
                       const float* __restrict__ W_ih, const float* __restrict__ b_ih,
                       const float* __restrict__ W_hh, const float* __restrict__ b_hh,
                       const float* __restrict__ W_tensor, double* __restrict__ ws) {
  int tid = blockIdx.x*blockDim.x + threadIdx.x;
  int nthr = gridDim.x*blockDim.x;
  double* h = ws + OFF_H; double* c = ws + OFF_C;
  double* Wcat = ws + OFF_WCAT; double* WtT = ws + OFF_WTT;
  double* bs = ws + OFF_BS;
  if (tid < 512) ((unsigned*)(ws + OFF_BAR))[tid] = 0u;
  for (int i = tid; i < NNODE*RCH; i += nthr) { h[i] = (double)h0[i]; c[i] = (double)c0[i]; }
  for (int i = tid; i < 512*256; i += nthr) {
    int kk = i & 255; int gc = i >> 8;
    Wcat[i] = (kk < 128) ? (double)W_ih[gc*128 + kk] : (double)W_hh[gc*128 + (kk-128)];
  }
  for (int i = tid; i < 2048*64; i += nthr) {
    int e = i & 63; int q2 = i >> 6;
    WtT[i] = (double)W_tensor[e*2048 + q2];
  }
  for (int i = tid; i < 512; i += nthr) bs[i] = (double)b_ih[i] + (double)b_hh[i];
}

// Device-scope grid barrier v3.
// Coherence ops ONCE per block per barrier (release fence before arrival,
// acquire fence after gate). Polls are RELAXED on 8 line-separated gates
// (64 pollers each) at ~0.85us period -> no coherence-point contention.
__device__ __forceinline__ void grid_sync(unsigned* bar, unsigned gen, int bid) {
  __syncthreads();
  if (threadIdx.x == 0) {
    __builtin_amdgcn_fence(__ATOMIC_RELEASE, "agent");
    const int lg = bid & (NLEAF-1);
    unsigned* leaf = bar + (lg << 4);
    unsigned prev = __hip_atomic_fetch_add(leaf, 1u, __ATOMIC_RELAXED,
                                           __HIP_MEMORY_SCOPE_AGENT);
    if (prev == (NBLK/NLEAF)-1u) {
      unsigned pr = __hip_atomic_fetch_add(bar+128, 1u, __ATOMIC_RELAXED,
                                           __HIP_MEMORY_SCOPE_AGENT);
      if (pr == NLEAF-1u) {
        #pragma unroll
        for (int i = 0; i < NLEAF; ++i)
          __hip_atomic_store(bar + (i<<4), 0u, __ATOMIC_RELAXED, __HIP_MEMORY_SCOPE_AGENT);
        __hip_atomic_store(bar+128, 0u, __ATOMIC_RELAXED, __HIP_MEMORY_SCOPE_AGENT);
        // order the resets before the gate-opens
        __builtin_amdgcn_fence(__ATOMIC_RELEASE, "agent");
        #pragma unroll
        for (int i = 0; i < NLEAF; ++i)
          __hip_atomic_store(bar + 160 + (i<<4), gen+1u, __ATOMIC_RELAXED,
                             __HIP_MEMORY_SCOPE_AGENT);
      }
    }
    unsigned* gate = bar + 160 + (lg<<4);
    if (__hip_atomic_load(gate, __ATOMIC_RELAXED, __HIP_MEMORY_SCOPE_AGENT) != gen+1u) {
      do {
        __builtin_amdgcn_s_sleep(32);
      } while (__hip_atomic_load(gate, __ATOMIC_RELAXED,
                                 __HIP_MEMORY_SCOPE_AGENT) != gen+1u);
    }
    __builtin_amdgcn_fence(__ATOMIC_ACQUIRE, "agent");
  }
  __syncthreads();
}

__global__ __launch_bounds__(256, 2) void k_steps(
    const float* __restrict__ nodes, const float* __restrict__ grids,
    const float* __restrict__ W_in, const float* __restrict__ b_in,
    const float* __restrict__ b_tensor,
    const float* __restrict__ W_out, const float* __restrict__ b_out,
    double* __restrict__ ws, float* __restrict__ outp,
    float* __restrict__ hf, float* __restrict__ cf) {
  __shared__ __align__(16) double smem[4672];
  double* __restrict__ h = ws + OFF_H;
  double* __restrict__ c = ws + OFF_C;
  double* __restrict__ Ht = ws + OFF_HT;
  double* __restrict__ part = ws + OFF_PART;
  const double* __restrict__ Wcat = ws + OFF_WCAT;
  const double* __restrict__ WtT = ws + OFF_WTT;
  const double* __restrict__ bs = ws + OFF_BS;
  unsigned* bar = (unsigned*)(ws + OFF_BAR);
  const int tid = threadIdx.x;
  const int bid = blockIdx.x;
  unsigned gen = 0;

  // ---- phase HT(t=0): Ht from h(0); no out ----
  {
    double (*h2b)[130] = (double(*)[130])smem;
    const int mc = bid >> 4, g = bid & 15;
    const int m0 = mc << 4;
    const int r = tid & 127;
    #pragma unroll
    for (int pass = 0; pass < 8; ++pass) {
      const int n = (tid >> 7) + (pass << 1);
      h2b[n][r] = h[(size_t)(m0+n)*RCH + r];
    }
    __syncthreads();
    const int e = tid & 63, mh = tid >> 6;
    const double* wt = WtT + (size_t)(g*128)*ECH + e;
    double acc[4] = {};
    #pragma unroll 4
    for (int rr = 0; rr < 128; ++rr) {
      double w0 = wt[(size_t)rr*ECH];
      #pragma unroll
      for (int mi = 0; mi < 4; ++mi) acc[mi] += h2b[(mh<<2)+mi][rr]*w0;
    }
    #pragma unroll
    for (int mi = 0; mi < 4; ++mi)
      Ht[((size_t)(m0+(mh<<2)+mi)*G2C + g)*ECH + e] = acc[mi];
  }
  grid_sync(bar, gen, bid); ++gen;

  for (int t = 0; t < TT; ++t) {
    // ---- phase SOCIAL: part[kc][n][e] ----
    {
      float* sgf = (float*)smem;
      const int kc = bid & (KSPLIT-1);
      const int n0 = (bid >> 4) << 4;
      const int kb = kc * KCH;
      const float* gbase = grids + (size_t)t*NNODE*KSOC;
      for (int i = tid; i < 16*128; i += 256) {
        int row = i >> 7; int c4 = i & 127;
        float4 v = *(const float4*)(gbase + (size_t)(n0+row)*KSOC + kb + (c4<<2));
        *(float4*)(&sgf[row*SGS + (c4<<2)]) = v;
      }
      __syncthreads();
      const int lane = tid & 63;
      const int wv = tid >> 6;
      const int e0 = (lane & 15) << 2;
      const int nq = lane >> 4;
      double acc[4][4] = {};
      const int kl0 = wv << 7;
      const double* htp = Ht + (size_t)(kb + kl0)*ECH + e0;
      #pragma unroll 2
      for (int kk = 0; kk < 128; kk += 2) {
        double2 b0a = *(const double2*)(htp + (size_t)kk*ECH);
        double2 b0b = *(const double2*)(htp + (size_t)kk*ECH + 2);
        double2 b1a = *(const double2*)(htp + (size_t)(kk+1)*ECH);
        double2 b1b = *(const double2*)(htp + (size_t)(kk+1)*ECH + 2);
        const int kl = kl0 + kk;
        #pragma unroll
        for (int jn = 0; jn < 4; ++jn) {
          float2 av2 = *(const float2*)(&sgf[((jn<<2)+nq)*SGS + kl]);
          double a0 = (double)av2.x, a1 = (double)av2.y;
          acc[jn][0] += a0*b0a.x + a1*b1a.x;
          acc[jn][1] += a0*b0a.y + a1*b1a.y;
          acc[jn][2] += a0*b0b.x + a1*b1b.x;
          acc[jn][3] += a0*b0b.y + a1*b1b.y;
        }
      }
      __syncthreads();
      if (wv > 0) {
        double* rp = smem + ((size_t)(wv-1)*64 + lane)*16;
        #pragma unroll
        for (int jn = 0; jn < 4; ++jn)
          #pragma unroll
          for (int je = 0; je < 4; ++je) rp[(jn<<2)+je] = acc[jn][je];
      }
      __syncthreads();
      if (wv == 0) {
        #pragma unroll
        for (int w = 0; w < 3; ++w) {
          const double* rp = smem + ((size_t)w*64 + lane)*16;
          #pragma unroll
          for (int jn = 0; jn < 4; ++jn)
            #pragma unroll
            for (int je = 0; je < 4; ++je) acc[jn][je] += rp[(jn<<2)+je];
        }
        #pragma unroll
        for (int jn = 0; jn < 4; ++jn) {
          double* pp = part + ((size_t)kc*NNODE + n0 + (jn<<2) + nq)*ECH + e0;
          pp[0]=acc[jn][0]; pp[1]=acc[jn][1]; pp[2]=acc[jn][2]; pp[3]=acc[jn][3];
        }
      }
    }
    grid_sync(bar, gen, bid); ++gen;

    // ---- phase CELL: gates + pointwise ----
    {
      double (*xh)[258] = (double(*)[258])smem;          // 16*258 = 4128
      double (*gbuf)[17] = (double(*)[17])(smem + 4128); // 32*17  = 544
      const int nc = bid >> 4;
      const int rc = bid & 15;
      const int m0 = nc << 4;
      {
        const int e = tid & 63;
        #pragma unroll
        for (int pass = 0; pass < 4; ++pass) {
          const int n = (tid >> 6) + (pass << 2);
          const int m = m0 + n;
          double te = (double)b_tensor[e];
          for (int kc = 0; kc < KSPLIT; ++kc)
            te += part[((size_t)kc*NNODE + m)*ECH + e];
          double n0v = (double)nodes[((size_t)t*NNODE + m)*ICH + 0];
          double n1v = (double)nodes[((size_t)t*NNODE + m)*ICH + 1];
          double ie = n0v*(double)W_in[e*2] + n1v*(double)W_in[e*2+1] + (double)b_in[e];
          xh[n][e] = fmax(ie, 0.0);
          xh[n][64+e] = fmax(te, 0.0);
        }
        const int r = tid & 127;
        #pragma unroll
        for (int pass = 0; pass < 8; ++pass) {
          const int n = (tid >> 7) + (pass << 1);
          xh[n][128+r] = h[(size_t)(m0+n)*RCH + r];
        }
      }
      __syncthreads();
      {
        const int n = tid & 15, tg = tid >> 4;
        const int q0 = tg >> 3, jr = tg & 7;
        const int gc0 = q0*128 + rc*8 + jr;
        const int gc1 = (q0+2)*128 + rc*8 + jr;
        const double* w0 = Wcat + (size_t)gc0*256;
        const double* w1 = Wcat + (size_t)gc1*256;
        double a0 = 0.0, a1 = 0.0;
        #pragma unroll 8
        for (int kk = 0; kk < 256; kk += 2) {
          double2 xv = *(const double2*)(&xh[n][kk]);
          double2 wa = *(const double2*)(w0 + kk);
          double2 wb = *(const double2*)(w1 + kk);
          a0 += xv.x*wa.x + xv.y*wa.y;
          a1 += xv.x*wb.x + xv.y*wb.y;
        }
        gbuf[tg][n]    = a0 + bs[gc0];
        gbuf[tg+16][n] = a1 + bs[gc1];
      }
      __syncthreads();
      if (tid < 128) {
        const int n = tid >> 3, jr = tid & 7;
        const int m = m0 + n, r = rc*8 + jr;
        double ig = sigd(gbuf[jr][n]);
        double fg = sigd(gbuf[8+jr][n]);
        double gg = tanh(gbuf[16+jr][n]);
        double og = sigd(gbuf[24+jr][n]);
        double cold = c[(size_t)m*RCH + r];
        double c2 = fg*cold + ig*gg;
        double h2v = og*tanh(c2);
        c[(size_t)m*RCH + r] = c2;
        h[(size_t)m*RCH + r] = h2v;
        if (t == TT-1) {
          hf[(size_t)m*RCH + r] = (float)h2v;
          cf[(size_t)m*RCH + r] = (float)c2;
        }
      }
    }
    grid_sync(bar, gen, bid); ++gen;

    // ---- phase HT+OUT: Ht(t+1) (skip at last t) + out[t] ----
    {
      double (*h2b)[130] = (double(*)[130])smem;
      const int mc = bid >> 4, g = bid & 15;
      const int m0 = mc << 4;
      const int r = tid & 127;
      #pragma unroll
      for (int pass = 0; pass < 8; ++pass) {
        const int n = (tid >> 7) + (pass << 1);
        h2b[n][r] = h[(size_t)(m0+n)*RCH + r];
      }
      __syncthreads();
      if (t < TT-1) {
        const int e = tid & 63, mh = tid >> 6;
        const double* wt = WtT + (size_t)(g*128)*ECH + e;
        double acc[4] = {};
        #pragma unroll 4
        for (int rr = 0; rr < 128; ++rr) {
          double w0 = wt[(size_t)rr*ECH];
          #pragma unroll
          for (int mi = 0; mi < 4; ++mi) acc[mi] += h2b[(mh<<2)+mi][rr]*w0;
        }
        #pragma unroll
        for (int mi = 0; mi < 4; ++mi)
          Ht[((size_t)(m0+(mh<<2)+mi)*G2C + g)*ECH + e] = acc[mi];
      }
      if (g == 0 && tid < 80) {
        const int mi = tid / OCH, oo = tid % OCH;
        double v = (double)b_out[oo];
        #pragma unroll 8
        for (int r2 = 0; r2 < 128; ++r2)
          v += h2b[mi][r2]*(double)W_out[oo*RCH + r2];
        outp[((size_t)t*NNODE + m0 + mi)*OCH + oo] = (float)v;
      }
    }
    if (t < TT-1) { grid_sync(bar, gen, bid); ++gen; }
  }
}

extern "C" void kernel_launch(void* const* d_in, const int* in_sizes, int n_in,
                              void* d_out, int out_size, void* d_ws, size_t ws_size,
                              hipStream_t stream) {
  const float* nodes    = (const float*)d_in[0];
  const float* grids    = (const float*)d_in[1];
  const float* h0       = (const float*)d_in[2];
  const float* c0       = (const float*)d_in[3];
  const float* W_in     = (const float*)d_in[4];
  const float* b_in     = (const float*)d_in[5];
  const float* W_tensor = (const float*)d_in[6];
  const float* b_tensor = (const float*)d_in[7];
  const float* W_ih     = (const float*)d_in[8];
  const float* b_ih     = (const float*)d_in[9];
  const float* W_hh     = (const float*)d_in[10];
  const float* b_hh     = (const float*)d_in[11];
  const float* W_out    = (const float*)d_in[12];
  const float* b_out    = (const float*)d_in[13];
  double* ws = (double*)d_ws;
  float* outp = (float*)d_out;                 // [20][512][5]
  float* hf = outp + (size_t)TT*NNODE*OCH;     // [512][128]
  float* cf = hf + (size_t)NNODE*RCH;          // [512][128]

  k_init<<<256, 256, 0, stream>>>(h0, c0, W_ih, b_ih, W_hh, b_hh, W_tensor, ws);
  k_steps<<<NBLK, 256, 0, stream>>>(nodes, grids, W_in, b_in, b_tensor,
                                    W_out, b_out, ws, outp, hf, cf);
}

// Round 7
// 2452.795 us; speedup vs baseline: 2.2274x; 1.2903x over previous
//
#include <hip/hip_runtime.h>

// Problem constants
#define TT 20
#define NNODE 512
#define G2C 16
#define RCH 128
#define ECH 64
#define ICH 2
#define OCH 5
#define KSOC 8192          // N*G2
#define KSPLIT 16
#define KCH 512            // KSOC/KSPLIT
#define SGS 516            // LDS f32 row stride in social phase (conflict-free)
#define NBLK 512
#define NLEAF 8

// workspace layout (double offsets)
#define OFF_H    0u         // h ping  [512*128]
#define OFF_C    65536u     // c       [512*128]
#define OFF_HT   131072u    // Ht      [8192][64]
#define OFF_PART 655360u    // part    [16][512][64]
#define OFF_WCAT 1179648u   // Wcat    [512 gc][256 kk]
#define OFF_WTT  1310720u   // WtT     [2048 q2][64 e]
#define OFF_BS   1441792u   // bs      [512 gc]
#define OFF_BAR  1442304u   // barrier words (512 unsigned = 256 doubles)
#define OFF_H2   1442560u   // h pong  [512*128]
// total 1508096 doubles = 12.06 MB

#define AT_LOADD(p)    __hip_atomic_load((p), __ATOMIC_RELAXED, __HIP_MEMORY_SCOPE_AGENT)
#define AT_STORED(p,v) __hip_atomic_store((p), (v), __ATOMIC_RELAXED, __HIP_MEMORY_SCOPE_AGENT)

__device__ __forceinline__ double sigd(double x){ return 1.0/(1.0+exp(-x)); }

__global__ void k_init(const float* __restrict__ h0, const float* __restrict__ c0,
                       const float* __restrict__ W_ih, const float* __restrict__ b_ih,
                       const float* __restrict__ W_hh, const float* __restrict__ b_hh,
                       const float* __restrict__ W_tensor, double* __restrict__ ws) {
  int tid = blockIdx.x*blockDim.x + threadIdx.x;
  int nthr = gridDim.x*blockDim.x;
  double* h = ws + OFF_H; double* c = ws + OFF_C;
  double* Wcat = ws + OFF_WCAT; double* WtT = ws + OFF_WTT;
  double* bs = ws + OFF_BS;
  if (tid < 512) ((unsigned*)(ws + OFF_BAR))[tid] = 0u;
  for (int i = tid; i < NNODE*RCH; i += nthr) { h[i] = (double)h0[i]; c[i] = (double)c0[i]; }
  for (int i = tid; i < 512*256; i += nthr) {
    int kk = i & 255; int gc = i >> 8;
    Wcat[i] = (kk < 128) ? (double)W_ih[gc*128 + kk] : (double)W_hh[gc*128 + (kk-128)];
  }
  for (int i = tid; i < 2048*64; i += nthr) {
    int e = i & 63; int q2 = i >> 6;
    WtT[i] = (double)W_tensor[e*2048 + q2];
  }
  for (int i = tid; i < 512; i += nthr) bs[i] = (double)b_ih[i] + (double)b_hh[i];
}

// Fence-free grid barrier: counters only. Correctness:
//  - __syncthreads() drains each wave's vmcnt before s_barrier, so ALL block
//    stores (the cross-phase ones are agent-coherent atomics -> complete at the
//    coherence point) are globally visible before tid0's arrival add.
//  - Readers access cross-phase data only via agent atomic loads (never served
//    by stale L1/L2), and in-order issue means they execute after the poll.
__device__ __forceinline__ void grid_sync(unsigned* bar, unsigned gen, int bid) {
  __syncthreads();
  if (threadIdx.x == 0) {
    __builtin_amdgcn_s_waitcnt(0);
    const int lg = bid & (NLEAF-1);
    unsigned prev = __hip_atomic_fetch_add(bar + (lg<<4), 1u, __ATOMIC_RELAXED,
                                           __HIP_MEMORY_SCOPE_AGENT);
    if (prev == (NBLK/NLEAF)-1u) {
      unsigned pr = __hip_atomic_fetch_add(bar+128, 1u, __ATOMIC_RELAXED,
                                           __HIP_MEMORY_SCOPE_AGENT);
      if (pr == NLEAF-1u) {
        #pragma unroll
        for (int i = 0; i < NLEAF; ++i)
          __hip_atomic_store(bar + (i<<4), 0u, __ATOMIC_RELAXED, __HIP_MEMORY_SCOPE_AGENT);
        __hip_atomic_store(bar+128, 0u, __ATOMIC_RELAXED, __HIP_MEMORY_SCOPE_AGENT);
        __builtin_amdgcn_s_waitcnt(0);   // resets land before gates open
        #pragma unroll
        for (int i = 0; i < NLEAF; ++i)
          __hip_atomic_store(bar + 160 + (i<<4), gen+1u, __ATOMIC_RELAXED,
                             __HIP_MEMORY_SCOPE_AGENT);
      }
    }
    unsigned* gate = bar + 160 + (lg<<4);
    if (__hip_atomic_load(gate, __ATOMIC_RELAXED, __HIP_MEMORY_SCOPE_AGENT) != gen+1u) {
      do {
        __builtin_amdgcn_s_sleep(16);
      } while (__hip_atomic_load(gate, __ATOMIC_RELAXED,
                                 __HIP_MEMORY_SCOPE_AGENT) != gen+1u);
    }
    asm volatile("" ::: "memory");
  }
  __syncthreads();
}

__global__ __launch_bounds__(256, 2) void k_steps(
    const float* __restrict__ nodes, const float* __restrict__ grids,
    const float* __restrict__ W_in, const float* __restrict__ b_in,
    const float* __restrict__ b_tensor,
    const float* __restrict__ W_out, const float* __restrict__ b_out,
    double* __restrict__ ws, float* __restrict__ outp,
    float* __restrict__ hf, float* __restrict__ cf) {
  __shared__ __align__(16) double smem[4672];
  double* __restrict__ c = ws + OFF_C;
  double* __restrict__ Ht = ws + OFF_HT;
  double* __restrict__ part = ws + OFF_PART;
  const double* __restrict__ Wcat = ws + OFF_WCAT;
  const double* __restrict__ WtT = ws + OFF_WTT;
  const double* __restrict__ bs = ws + OFF_BS;
  unsigned* bar = (unsigned*)(ws + OFF_BAR);
  const int tid = threadIdx.x;
  const int bid = blockIdx.x;
  unsigned gen = 0;

  // ---- phase HT(t=0): Ht from h(0) ----
  {
    double (*h2b)[130] = (double(*)[130])smem;
    const double* hsrc = ws + OFF_H;
    const int mc = bid >> 4, g = bid & 15;
    const int m0 = mc << 4;
    const int r = tid & 127;
    #pragma unroll
    for (int pass = 0; pass < 8; ++pass) {
      const int n = (tid >> 7) + (pass << 1);
      h2b[n][r] = AT_LOADD(hsrc + (size_t)(m0+n)*RCH + r);
    }
    __syncthreads();
    const int e = tid & 63, mh = tid >> 6;
    const double* wt = WtT + (size_t)(g*128)*ECH + e;
    double acc[4] = {};
    #pragma unroll 4
    for (int rr = 0; rr < 128; ++rr) {
      double w0 = wt[(size_t)rr*ECH];
      #pragma unroll
      for (int mi = 0; mi < 4; ++mi) acc[mi] += h2b[(mh<<2)+mi][rr]*w0;
    }
    #pragma unroll
    for (int mi = 0; mi < 4; ++mi)
      AT_STORED(Ht + ((size_t)(m0+(mh<<2)+mi)*G2C + g)*ECH + e, acc[mi]);
  }
  grid_sync(bar, gen, bid); ++gen;

  for (int t = 0; t < TT; ++t) {
    const double* hcur = ws + ((t & 1) ? OFF_H2 : OFF_H);
    double*       hnxt = ws + ((t & 1) ? OFF_H  : OFF_H2);

    // ---- phase SOCIAL: part[kc][n][e] ----
    {
      float* sgf = (float*)smem;
      const int kc = bid & (KSPLIT-1);
      const int n0 = (bid >> 4) << 4;
      const int kb = kc * KCH;
      const float* gbase = grids + (size_t)t*NNODE*KSOC;
      for (int i = tid; i < 16*128; i += 256) {
        int row = i >> 7; int c4 = i & 127;
        float4 v = *(const float4*)(gbase + (size_t)(n0+row)*KSOC + kb + (c4<<2));
        *(float4*)(&sgf[row*SGS + (c4<<2)]) = v;
      }
      __syncthreads();
      const int lane = tid & 63;
      const int wv = tid >> 6;
      const int e0 = (lane & 15) << 2;
      const int nq = lane >> 4;
      double acc[4][4] = {};
      const int kl0 = wv << 7;
      const double* htp = Ht + (size_t)(kb + kl0)*ECH + e0;
      #pragma unroll 2
      for (int kk = 0; kk < 128; kk += 2) {
        const double* hp0 = htp + (size_t)kk*ECH;
        const double* hp1 = hp0 + ECH;
        double b00 = AT_LOADD(hp0+0), b01 = AT_LOADD(hp0+1);
        double b02 = AT_LOADD(hp0+2), b03 = AT_LOADD(hp0+3);
        double b10 = AT_LOADD(hp1+0), b11 = AT_LOADD(hp1+1);
        double b12 = AT_LOADD(hp1+2), b13 = AT_LOADD(hp1+3);
        const int kl = kl0 + kk;
        #pragma unroll
        for (int jn = 0; jn < 4; ++jn) {
          float2 av2 = *(const float2*)(&sgf[((jn<<2)+nq)*SGS + kl]);
          double a0 = (double)av2.x, a1 = (double)av2.y;
          acc[jn][0] += a0*b00 + a1*b10;
          acc[jn][1] += a0*b01 + a1*b11;
          acc[jn][2] += a0*b02 + a1*b12;
          acc[jn][3] += a0*b03 + a1*b13;
        }
      }
      __syncthreads();
      if (wv > 0) {
        double* rp = smem + ((size_t)(wv-1)*64 + lane)*16;
        #pragma unroll
        for (int jn = 0; jn < 4; ++jn)
          #pragma unroll
          for (int je = 0; je < 4; ++je) rp[(jn<<2)+je] = acc[jn][je];
      }
      __syncthreads();
      if (wv == 0) {
        #pragma unroll
        for (int w = 0; w < 3; ++w) {
          const double* rp = smem + ((size_t)w*64 + lane)*16;
          #pragma unroll
          for (int jn = 0; jn < 4; ++jn)
            #pragma unroll
            for (int je = 0; je < 4; ++je) acc[jn][je] += rp[(jn<<2)+je];
        }
        #pragma unroll
        for (int jn = 0; jn < 4; ++jn) {
          double* pp = part + ((size_t)kc*NNODE + n0 + (jn<<2) + nq)*ECH + e0;
          AT_STORED(pp+0, acc[jn][0]); AT_STORED(pp+1, acc[jn][1]);
          AT_STORED(pp+2, acc[jn][2]); AT_STORED(pp+3, acc[jn][3]);
        }
      }
    }
    grid_sync(bar, gen, bid); ++gen;

    // ---- phase CELL: gates + pointwise; reads hcur, writes hnxt ----
    {
      double (*xh)[258] = (double(*)[258])smem;          // 16*258 = 4128
      double (*gbuf)[17] = (double(*)[17])(smem + 4128); // 32*17  = 544
      const int nc = bid >> 4;
      const int rc = bid & 15;
      const int m0 = nc << 4;
      {
        const int e = tid & 63;
        #pragma unroll
        for (int pass = 0; pass < 4; ++pass) {
          const int n = (tid >> 6) + (pass << 2);
          const int m = m0 + n;
          double te = (double)b_tensor[e];
          #pragma unroll
          for (int kc = 0; kc < KSPLIT; ++kc)
            te += AT_LOADD(part + ((size_t)kc*NNODE + m)*ECH + e);
          double n0v = (double)nodes[((size_t)t*NNODE + m)*ICH + 0];
          double n1v = (double)nodes[((size_t)t*NNODE + m)*ICH + 1];
          double ie = n0v*(double)W_in[e*2] + n1v*(double)W_in[e*2+1] + (double)b_in[e];
          xh[n][e] = fmax(ie, 0.0);
          xh[n][64+e] = fmax(te, 0.0);
        }
        const int r = tid & 127;
        #pragma unroll
        for (int pass = 0; pass < 8; ++pass) {
          const int n = (tid >> 7) + (pass << 1);
          xh[n][128+r] = AT_LOADD(hcur + (size_t)(m0+n)*RCH + r);
        }
      }
      __syncthreads();
      {
        const int n = tid & 15, tg = tid >> 4;
        const int q0 = tg >> 3, jr = tg & 7;
        const int gc0 = q0*128 + rc*8 + jr;
        const int gc1 = (q0+2)*128 + rc*8 + jr;
        const double* w0 = Wcat + (size_t)gc0*256;
        const double* w1 = Wcat + (size_t)gc1*256;
        double a0 = 0.0, a1 = 0.0;
        #pragma unroll 8
        for (int kk = 0; kk < 256; kk += 2) {
          double2 xv = *(const double2*)(&xh[n][kk]);
          double2 wa = *(const double2*)(w0 + kk);
          double2 wb = *(const double2*)(w1 + kk);
          a0 += xv.x*wa.x + xv.y*wa.y;
          a1 += xv.x*wb.x + xv.y*wb.y;
        }
        gbuf[tg][n]    = a0 + bs[gc0];
        gbuf[tg+16][n] = a1 + bs[gc1];
      }
      __syncthreads();
      if (tid < 128) {
        const int n = tid >> 3, jr = tid & 7;
        const int m = m0 + n, r = rc*8 + jr;
        double ig = sigd(gbuf[jr][n]);
        double fg = sigd(gbuf[8+jr][n]);
        double gg = tanh(gbuf[16+jr][n]);
        double og = sigd(gbuf[24+jr][n]);
        double cold = c[(size_t)m*RCH + r];
        double c2 = fg*cold + ig*gg;
        double h2v = og*tanh(c2);
        c[(size_t)m*RCH + r] = c2;
        AT_STORED(hnxt + (size_t)m*RCH + r, h2v);
        if (t == TT-1) {
          hf[(size_t)m*RCH + r] = (float)h2v;
          cf[(size_t)m*RCH + r] = (float)c2;
        }
      }
    }
    grid_sync(bar, gen, bid); ++gen;

    // ---- phase HT+OUT: Ht(t+1) from hnxt (skip at last t) + out[t] ----
    {
      double (*h2b)[130] = (double(*)[130])smem;
      const int mc = bid >> 4, g = bid & 15;
      const int m0 = mc << 4;
      const int r = tid & 127;
      #pragma unroll
      for (int pass = 0; pass < 8; ++pass) {
        const int n = (tid >> 7) + (pass << 1);
        h2b[n][r] = AT_LOADD(hnxt + (size_t)(m0+n)*RCH + r);
      }
      __syncthreads();
      if (t < TT-1) {
        const int e = tid & 63, mh = tid >> 6;
        const double* wt = WtT + (size_t)(g*128)*ECH + e;
        double acc[4] = {};
        #pragma unroll 4
        for (int rr = 0; rr < 128; ++rr) {
          double w0 = wt[(size_t)rr*ECH];
          #pragma unroll
          for (int mi = 0; mi < 4; ++mi) acc[mi] += h2b[(mh<<2)+mi][rr]*w0;
        }
        #pragma unroll
        for (int mi = 0; mi < 4; ++mi)
          AT_STORED(Ht + ((size_t)(m0+(mh<<2)+mi)*G2C + g)*ECH + e, acc[mi]);
      }
      if (g == 0 && tid < 80) {
        const int mi = tid / OCH, oo = tid % OCH;
        double v = (double)b_out[oo];
        #pragma unroll 8
        for (int r2 = 0; r2 < 128; ++r2)
          v += h2b[mi][r2]*(double)W_out[oo*RCH + r2];
        outp[((size_t)t*NNODE + m0 + mi)*OCH + oo] = (float)v;
      }
    }
    if (t < TT-1) { grid_sync(bar, gen, bid); ++gen; }
  }
}

extern "C" void kernel_launch(void* const* d_in, const int* in_sizes, int n_in,
                              void* d_out, int out_size, void* d_ws, size_t ws_size,
                              hipStream_t stream) {
  const float* nodes    = (const float*)d_in[0];
  const float* grids    = (const float*)d_in[1];
  const float* h0       = (const float*)d_in[2];
  const float* c0       = (const float*)d_in[3];
  const float* W_in     = (const float*)d_in[4];
  const float* b_in     = (const float*)d_in[5];
  const float* W_tensor = (const float*)d_in[6];
  const float* b_tensor = (const float*)d_in[7];
  const float* W_ih     = (const float*)d_in[8];
  const float* b_ih     = (const float*)d_in[9];
  const float* W_hh     = (const float*)d_in[10];
  const float* b_hh     = (const float*)d_in[11];
  const float* W_out    = (const float*)d_in[12];
  const float* b_out    = (const float*)d_in[13];
  double* ws = (double*)d_ws;
  float* outp = (float*)d_out;                 // [20][512][5]
  float* hf = outp + (size_t)TT*NNODE*OCH;     // [512][128]
  float* cf = hf + (size_t)NNODE*RCH;          // [512][128]

  k_init<<<256, 256, 0, stream>>>(h0, c0, W_ih, b_ih, W_hh, b_hh, W_tensor, ws);
  k_steps<<<NBLK, 256, 0, stream>>>(nodes, grids, W_in, b_in, b_tensor,
                                    W_out, b_out, ws, outp, hf, cf);
}